// Round 1
// baseline (3937.356 us; speedup 1.0000x reference)
//
#include <hip/hip_runtime.h>
#include <hip/hip_bf16.h>
#include <stdint.h>

#define NTOK 8192   // B*T
#define DM   1024   // model dim
#define NE   8      // experts
#define DI   2048   // expert inner dim
#define NL   2      // layers
#define NV   32000  // vocab

typedef __attribute__((ext_vector_type(8))) __bf16 bf16x8;
typedef __attribute__((ext_vector_type(4))) float  f32x4;
typedef unsigned short u16;

__device__ __forceinline__ u16 f2bf(float f) {
  uint32_t u = __builtin_bit_cast(uint32_t, f);
  return (u16)((u + 0x7fffu + ((u >> 16) & 1u)) >> 16);  // RNE
}

__device__ __forceinline__ void gload_lds16(const u16* g, u16* l) {
  __builtin_amdgcn_global_load_lds(
      (const __attribute__((address_space(1))) void*)g,
      (__attribute__((address_space(3))) void*)l, 16, 0, 0);
}

// ---------------------------------------------------------------------------
// GEMM mainloop: C[128x128] tile = A[rowBase..+128, K] * B[colBase..+128, K]^T
// A, B both row-major bf16 with leading dim K (B is the pre-transposed weight).
// LDS layout per tile: [kg (k/8)][m (128)][8 k] -> staging linear, ds_read_b128
// conflict-free. Double-buffered, one barrier per K-step (m97-class structure).
// ---------------------------------------------------------------------------
__device__ __forceinline__ void gemm_bt_loop(const u16* __restrict__ A,
                                             const u16* __restrict__ B,
                                             int K, int rowBase, int colBase,
                                             f32x4 (&acc)[4][4]) {
  __shared__ u16 sA[2][4096];
  __shared__ u16 sB[2][4096];
  const int t    = threadIdx.x;
  const int lane = t & 63;
  const int kg   = lane >> 4;   // 0..3 (k-group of 8)
  const int fr   = lane & 15;   // fragment row/col
  const int wave = t >> 6;
  const int wr   = (wave >> 1) << 6;  // wave row offset (0/64)
  const int wc   = (wave & 1) << 6;   // wave col offset (0/64)

  // staging chunks: chunk c (0..511) = 16B = row (c&127), kgroup (c>>7)
  const int c0 = t, c1 = t + 256;
  const int kg0 = c0 >> 7, m0 = c0 & 127;
  const int kg1 = c1 >> 7, m1 = c1 & 127;
  const u16* ga0 = A + (size_t)(rowBase + m0) * K + kg0 * 8;
  const u16* ga1 = A + (size_t)(rowBase + m1) * K + kg1 * 8;
  const u16* gb0 = B + (size_t)(colBase + m0) * K + kg0 * 8;
  const u16* gb1 = B + (size_t)(colBase + m1) * K + kg1 * 8;

  gload_lds16(ga0, &sA[0][c0 * 8]);
  gload_lds16(ga1, &sA[0][c1 * 8]);
  gload_lds16(gb0, &sB[0][c0 * 8]);
  gload_lds16(gb1, &sB[0][c1 * 8]);
  __syncthreads();

  const int nst = K >> 5;
  int cur = 0;
  for (int ks = 0; ks < nst; ++ks) {
    if (ks + 1 < nst) {  // prefetch next K-step into other buffer
      int ko = (ks + 1) << 5;
      gload_lds16(ga0 + ko, &sA[cur ^ 1][c0 * 8]);
      gload_lds16(ga1 + ko, &sA[cur ^ 1][c1 * 8]);
      gload_lds16(gb0 + ko, &sB[cur ^ 1][c0 * 8]);
      gload_lds16(gb1 + ko, &sB[cur ^ 1][c1 * 8]);
    }
    const u16* At = sA[cur];
    const u16* Bt = sB[cur];
    bf16x8 av[4], bv[4];
    const int ao = kg * 1024 + (wr + fr) * 8;
    const int bo = kg * 1024 + (wc + fr) * 8;
#pragma unroll
    for (int i = 0; i < 4; ++i) av[i] = *(const bf16x8*)(At + ao + i * 128);
#pragma unroll
    for (int i = 0; i < 4; ++i) bv[i] = *(const bf16x8*)(Bt + bo + i * 128);
#pragma unroll
    for (int mi = 0; mi < 4; ++mi)
#pragma unroll
      for (int ni = 0; ni < 4; ++ni)
        acc[mi][ni] = __builtin_amdgcn_mfma_f32_16x16x32_bf16(
            av[mi], bv[ni], acc[mi][ni], 0, 0, 0);
    __syncthreads();
    cur ^= 1;
  }
}

// GEMM1: e_act = gelu_erf(xn @ w1) -> bf16 [NTOK][DI] (per expert z)
__global__ __launch_bounds__(256) void k_gemm1(const u16* __restrict__ A,
                                               const u16* __restrict__ W,
                                               u16* __restrict__ Eo,
                                               size_t wStride, size_t eoStride) {
  f32x4 acc[4][4] = {};
  const int rowBase = blockIdx.y << 7, colBase = blockIdx.x << 7;
  const u16* Wz = W + (size_t)blockIdx.z * wStride;
  u16* Ez = Eo + (size_t)blockIdx.z * eoStride;
  gemm_bt_loop(A, Wz, DM, rowBase, colBase, acc);
  const int t = threadIdx.x, lane = t & 63, wave = t >> 6;
  const int row0 = rowBase + ((wave >> 1) << 6) + ((lane >> 4) << 2);
  const int col0 = colBase + ((wave & 1) << 6) + (lane & 15);
#pragma unroll
  for (int mi = 0; mi < 4; ++mi)
#pragma unroll
    for (int ni = 0; ni < 4; ++ni) {
      const int col = col0 + ni * 16;
#pragma unroll
      for (int i = 0; i < 4; ++i) {
        float v = acc[mi][ni][i];
        v = 0.5f * v * (1.0f + erff(v * 0.70710678118654752f));
        Ez[(size_t)(row0 + mi * 16 + i) * DI + col] = f2bf(v);
      }
    }
}

// GEMM2: eo = e_act @ w2 -> f32 directly into experts output region
// out row stride = NE*DM (experts layout [l][n][e][d]); z-expert offset z*DM
__global__ __launch_bounds__(256) void k_gemm2(const u16* __restrict__ Ein,
                                               const u16* __restrict__ W,
                                               float* __restrict__ out,
                                               size_t aStride, size_t wStride) {
  f32x4 acc[4][4] = {};
  const int rowBase = blockIdx.y << 7, colBase = blockIdx.x << 7;
  const u16* Az = Ein + (size_t)blockIdx.z * aStride;
  const u16* Wz = W + (size_t)blockIdx.z * wStride;
  float* oz = out + (size_t)blockIdx.z * DM;
  gemm_bt_loop(Az, Wz, DI, rowBase, colBase, acc);
  const int t = threadIdx.x, lane = t & 63, wave = t >> 6;
  const int row0 = rowBase + ((wave >> 1) << 6) + ((lane >> 4) << 2);
  const int col0 = colBase + ((wave & 1) << 6) + (lane & 15);
#pragma unroll
  for (int mi = 0; mi < 4; ++mi)
#pragma unroll
    for (int ni = 0; ni < 4; ++ni) {
      const int col = col0 + ni * 16;
#pragma unroll
      for (int i = 0; i < 4; ++i)
        oz[(size_t)(row0 + mi * 16 + i) * (NE * DM) + col] = acc[mi][ni][i];
    }
}

// Head: logits = h_bf @ head_w^T + head_b -> f32 [NTOK][NV]
__global__ __launch_bounds__(256) void k_head(const u16* __restrict__ A,
                                              const u16* __restrict__ W,
                                              const float* __restrict__ bias,
                                              float* __restrict__ out) {
  f32x4 acc[4][4] = {};
  const int rowBase = blockIdx.y << 7, colBase = blockIdx.x << 7;
  gemm_bt_loop(A, W, DM, rowBase, colBase, acc);
  const int t = threadIdx.x, lane = t & 63, wave = t >> 6;
  const int row0 = rowBase + ((wave >> 1) << 6) + ((lane >> 4) << 2);
  const int col0 = colBase + ((wave & 1) << 6) + (lane & 15);
#pragma unroll
  for (int mi = 0; mi < 4; ++mi)
#pragma unroll
    for (int ni = 0; ni < 4; ++ni) {
      const int col = col0 + ni * 16;
      const float bv = bias[col];
#pragma unroll
      for (int i = 0; i < 4; ++i)
        out[(size_t)(row0 + mi * 16 + i) * NV + col] = acc[mi][ni][i] + bv;
    }
}

// transpose+convert: in f32 [z][R][C] -> out bf16 [z][C][R]
__global__ void k_transcvt(const float* __restrict__ in, u16* __restrict__ out,
                           int R, int C) {
  const size_t bo = (size_t)blockIdx.z * R * C;
  in += bo; out += bo;
  __shared__ u16 tile[32][33];
  const int tx = threadIdx.x, ty = threadIdx.y;
  const int r0 = blockIdx.y << 5, c0 = blockIdx.x << 5;
#pragma unroll
  for (int j = 0; j < 4; ++j) {
    const int r = r0 + ty + j * 8;
    tile[ty + j * 8][tx] = f2bf(in[(size_t)r * C + c0 + tx]);
  }
  __syncthreads();
#pragma unroll
  for (int j = 0; j < 4; ++j) {
    const int c = c0 + ty + j * 8;
    out[(size_t)c * R + r0 + tx] = tile[tx][ty + j * 8];
  }
}

// embedding gather: h[n][:] = emb[x[n]][:]
__global__ void k_gather(const int* __restrict__ x, const float* __restrict__ emb,
                         float* __restrict__ h) {
  const int n = blockIdx.x, t = threadIdx.x;
  const int id = x[n];
  ((float4*)(h + (size_t)n * DM))[t] = ((const float4*)(emb + (size_t)id * DM))[t];
}

// fused LayerNorm (f32) -> xn bf16, + gating logits + softmax -> rw
__global__ void k_lngate(const float* __restrict__ h, const float* __restrict__ g,
                         const float* __restrict__ b, const float* __restrict__ gw,
                         const float* __restrict__ gb, u16* __restrict__ xnb,
                         float* __restrict__ rw) {
  const int n = blockIdx.x, t = threadIdx.x;
  const int wave = t >> 6, lane = t & 63;
  const float4 v = ((const float4*)(h + (size_t)n * DM))[t];
  float s = v.x + v.y + v.z + v.w;
  float q = v.x * v.x + v.y * v.y + v.z * v.z + v.w * v.w;
#pragma unroll
  for (int o = 32; o; o >>= 1) { s += __shfl_down(s, o, 64); q += __shfl_down(q, o, 64); }
  __shared__ float red[8];
  if (lane == 0) { red[wave] = s; red[wave + 4] = q; }
  __syncthreads();
  s = red[0] + red[1] + red[2] + red[3];
  q = red[4] + red[5] + red[6] + red[7];
  const float mu = s * (1.0f / DM);
  const float var = q * (1.0f / DM) - mu * mu;
  const float rs = rsqrtf(var + 1e-5f);
  const float4 gg = ((const float4*)g)[t];
  const float4 bb = ((const float4*)b)[t];
  float xv[4];
  xv[0] = (v.x - mu) * rs * gg.x + bb.x;
  xv[1] = (v.y - mu) * rs * gg.y + bb.y;
  xv[2] = (v.z - mu) * rs * gg.z + bb.z;
  xv[3] = (v.w - mu) * rs * gg.w + bb.w;
  ushort4 o4;
  o4.x = f2bf(xv[0]); o4.y = f2bf(xv[1]); o4.z = f2bf(xv[2]); o4.w = f2bf(xv[3]);
  ((ushort4*)(xnb + (size_t)n * DM))[t] = o4;
  // gating partials: gw is [D][E] row-major
  float p[8];
#pragma unroll
  for (int e = 0; e < 8; ++e) p[e] = 0.0f;
  const float* gwp = gw + (size_t)t * 32;
#pragma unroll
  for (int j = 0; j < 4; ++j)
#pragma unroll
    for (int e = 0; e < 8; ++e) p[e] += xv[j] * gwp[j * 8 + e];
#pragma unroll
  for (int e = 0; e < 8; ++e)
#pragma unroll
    for (int o = 32; o; o >>= 1) p[e] += __shfl_down(p[e], o, 64);
  __shared__ float pr[4][8];
  if (lane == 0) {
#pragma unroll
    for (int e = 0; e < 8; ++e) pr[wave][e] = p[e];
  }
  __syncthreads();
  if (t == 0) {
    float lg[8], m = -1e30f;
#pragma unroll
    for (int e = 0; e < 8; ++e) {
      lg[e] = pr[0][e] + pr[1][e] + pr[2][e] + pr[3][e] + gb[e];
      m = fmaxf(m, lg[e]);
    }
    float ss = 0.0f;
#pragma unroll
    for (int e = 0; e < 8; ++e) { lg[e] = expf(lg[e] - m); ss += lg[e]; }
    const float inv = 1.0f / ss;
#pragma unroll
    for (int e = 0; e < 8; ++e) rw[(size_t)n * NE + e] = lg[e] * inv;
  }
}

// h += sum_e rw[n][e] * eo[n][e][:]; also emit h in bf16 for the head GEMM
__global__ void k_agg(float* __restrict__ h, u16* __restrict__ hbf,
                      const float* __restrict__ eo, const float* __restrict__ rw) {
  const int n = blockIdx.x, t = threadIdx.x;
  float w[8];
#pragma unroll
  for (int e = 0; e < 8; ++e) w[e] = rw[(size_t)n * NE + e];
  const float4* eo4 = (const float4*)(eo + (size_t)n * NE * DM);
  float4 a = ((float4*)(h + (size_t)n * DM))[t];
#pragma unroll
  for (int e = 0; e < 8; ++e) {
    const float4 x = eo4[e * (DM / 4) + t];
    a.x += w[e] * x.x; a.y += w[e] * x.y; a.z += w[e] * x.z; a.w += w[e] * x.w;
  }
  ((float4*)(h + (size_t)n * DM))[t] = a;
  ushort4 o4;
  o4.x = f2bf(a.x); o4.y = f2bf(a.y); o4.z = f2bf(a.z); o4.w = f2bf(a.w);
  ((ushort4*)(hbf + (size_t)n * DM))[t] = o4;
}

extern "C" void kernel_launch(void* const* d_in, const int* in_sizes, int n_in,
                              void* d_out, int out_size, void* d_ws, size_t ws_size,
                              hipStream_t stream) {
  const int*   x      = (const int*)d_in[0];
  const float* emb    = (const float*)d_in[1];
  const float* ln_g   = (const float*)d_in[2];
  const float* ln_b   = (const float*)d_in[3];
  const float* gate_w = (const float*)d_in[4];
  const float* gate_b = (const float*)d_in[5];
  const float* w1     = (const float*)d_in[6];
  const float* w2     = (const float*)d_in[7];
  const float* head_w = (const float*)d_in[8];
  const float* head_b = (const float*)d_in[9];

  float* logits  = (float*)d_out;
  float* experts = logits + (size_t)NTOK * NV;

  char* p = (char*)d_ws;
  auto carve = [&](size_t bytes) -> void* {
    void* r = (void*)p; p += (bytes + 255) & ~(size_t)255; return r;
  };
  float* h   = (float*)carve((size_t)NTOK * DM * 4);
  u16*   hbf = (u16*)  carve((size_t)NTOK * DM * 2);
  u16*   xnb = (u16*)  carve((size_t)NTOK * DM * 2);
  float* rw  = (float*)carve((size_t)NTOK * NE * 4);
  u16*   w1t = (u16*)  carve((size_t)NE * DM * DI * 2);
  u16*   w2t = (u16*)  carve((size_t)NE * DM * DI * 2);
  u16*   hwt = (u16*)  carve((size_t)NV * DM * 2);
  const size_t fixed = (size_t)(p - (char*)d_ws);
  const size_t eactOne = (size_t)NTOK * DI * 2;
  const bool batched = ws_size >= fixed + eactOne * NE;
  u16* eact = (u16*)carve(batched ? eactOne * NE : eactOne);

  k_gather<<<dim3(NTOK), dim3(256), 0, stream>>>(x, emb, h);

  for (int l = 0; l < NL; ++l) {
    k_lngate<<<dim3(NTOK), dim3(256), 0, stream>>>(
        h, ln_g + (size_t)l * DM, ln_b + (size_t)l * DM,
        gate_w + (size_t)l * DM * NE, gate_b + (size_t)l * NE, xnb, rw);
    // w1[l]: [E][DM][DI] -> w1t [E][DI][DM]
    k_transcvt<<<dim3(DI / 32, DM / 32, NE), dim3(32, 8), 0, stream>>>(
        w1 + (size_t)l * NE * DM * DI, w1t, DM, DI);
    // w2[l]: [E][DI][DM] -> w2t [E][DM][DI]
    k_transcvt<<<dim3(DM / 32, DI / 32, NE), dim3(32, 8), 0, stream>>>(
        w2 + (size_t)l * NE * DM * DI, w2t, DI, DM);
    float* expertsL = experts + (size_t)l * NTOK * NE * DM;
    if (batched) {
      k_gemm1<<<dim3(DI / 128, NTOK / 128, NE), dim3(256), 0, stream>>>(
          xnb, w1t, eact, (size_t)DM * DI, (size_t)NTOK * DI);
      k_gemm2<<<dim3(DM / 128, NTOK / 128, NE), dim3(256), 0, stream>>>(
          eact, w2t, expertsL, (size_t)NTOK * DI, (size_t)DM * DI);
    } else {
      for (int e = 0; e < NE; ++e) {
        k_gemm1<<<dim3(DI / 128, NTOK / 128, 1), dim3(256), 0, stream>>>(
            xnb, w1t + (size_t)e * DM * DI, eact, 0, 0);
        k_gemm2<<<dim3(DM / 128, NTOK / 128, 1), dim3(256), 0, stream>>>(
            eact, w2t + (size_t)e * DM * DI, expertsL + (size_t)e * DM, 0, 0);
      }
    }
    k_agg<<<dim3(NTOK), dim3(256), 0, stream>>>(h, hbf, expertsL, rw);
  }

  // head_w [DM][NV] -> hwt [NV][DM]
  k_transcvt<<<dim3(NV / 32, DM / 32, 1), dim3(32, 8), 0, stream>>>(head_w, hwt, DM, NV);
  k_head<<<dim3(NV / 128, NTOK / 128, 1), dim3(256), 0, stream>>>(hbf, hwt, head_b, logits);
}

// Round 2
// 2719.890 us; speedup vs baseline: 1.4476x; 1.4476x over previous
//
#include <hip/hip_runtime.h>
#include <hip/hip_bf16.h>
#include <stdint.h>

#define NTOK 8192   // B*T
#define DM   1024   // model dim
#define NE   8      // experts
#define DI   2048   // expert inner dim
#define NL   2      // layers
#define NV   32000  // vocab

typedef __attribute__((ext_vector_type(8))) __bf16 bf16x8;
typedef __attribute__((ext_vector_type(4))) float  f32x4;
typedef unsigned short u16;

__device__ __forceinline__ u16 f2bf(float f) {
  uint32_t u = __builtin_bit_cast(uint32_t, f);
  return (u16)((u + 0x7fffu + ((u >> 16) & 1u)) >> 16);  // RNE
}

__device__ __forceinline__ void gload_lds16(const u16* g, u16* l) {
  __builtin_amdgcn_global_load_lds(
      (const __attribute__((address_space(1))) void*)g,
      (__attribute__((address_space(3))) void*)l, 16, 0, 0);
}

// bijective chunked XCD swizzle (m204): XCD x=orig&7 gets a contiguous logical range
__device__ __forceinline__ int xcd_swz(int orig, int nwg) {
  const int x = orig & 7, i = orig >> 3;
  const int q = nwg >> 3, r = nwg & 7;
  return (x < r ? x * (q + 1) : r * (q + 1) + (x - r) * q) + i;
}

// ---------------------------------------------------------------------------
// 256x256 tile GEMM, BK=64, 8 waves (2M x 4N), 128 KB LDS double-buffer.
// A [M][K], W [N][K] row-major bf16. Per K-tile: 4 phases, each
// {ds_read quadrant frags | stage prefetch | s_barrier | setprio(1) 16 MFMA
//  setprio(0) | s_barrier}; vmcnt(0) once per tile (issued >=3 phases early).
// st_16x32 LDS swizzle: linear dest + inverse-swizzled global src + swz read.
// EPI: 0 = +bias -> f32 (head), 1 = gelu -> bf16 (gemm1), 2 = f32 strided.
// ---------------------------------------------------------------------------
template <int EPI>
__global__ __launch_bounds__(512) void k_gemm256(
    const u16* __restrict__ Abase, const u16* __restrict__ Wbase,
    void* __restrict__ Obase, const float* __restrict__ bias,
    int K, int mBlks, int nBlks,
    size_t aStride, size_t wStride, size_t oStride, int ldOut) {
  extern __shared__ u16 lds[];  // 131072 B: A tiles [2][32KB], then B tiles
  const int logical = xcd_swz(blockIdx.x, gridDim.x);
  const int perE = mBlks * nBlks;
  const int e    = logical / perE;
  const int rem  = logical - e * perE;
  const int nb   = rem / mBlks;        // n-strip outer
  const int mb   = rem - nb * mBlks;   // m inner -> B-strip reuse per XCD chunk
  const int rowBase = mb << 8;
  const int colBase = nb << 8;
  const u16* A = Abase + (size_t)e * aStride;
  const u16* W = Wbase + (size_t)e * wStride;

  const int t = threadIdx.x;
  const int lane = t & 63, wave = t >> 6;
  const int wm = wave >> 2, wn = wave & 3;   // wave tile: rows wm*128, cols wn*64
  const int fr = lane & 15, kg = lane >> 4;

  char* sA = (char*)lds;            // per buf: 32768 B (2 halves x 128 rows x 128 B)
  char* sB = (char*)lds + 65536;

  // --- staging precompute: chunk c -> linear LDS dest, inverse-swz global src
  const u16* gA[4]; const u16* gB[4]; int ldsOff[4];
#pragma unroll
  for (int i = 0; i < 4; ++i) {
    const int c     = i * 512 + t;
    const int phys  = c * 16;              // byte within 32 KB tile
    const int half  = phys >> 14;
    const int local = phys & 16383;
    const int src   = local ^ (((local >> 9) & 1) << 5);
    const int r     = half * 128 + (src >> 7);
    const int kB    = src & 127;
    gA[i] = A + (size_t)(rowBase + r) * K + (kB >> 1);
    gB[i] = W + (size_t)(colBase + r) * K + (kB >> 1);
    ldsOff[i] = phys;
  }

  // --- fragment read bases (swizzle bit depends only on fr)
  const int swz      = ((fr >> 2) & 1) << 5;
  const int aLaneOff = (fr * 128 + kg * 16) ^ swz;
  const int bLaneOff = ((((wn & 1) * 64 + fr) * 128) + kg * 16) ^ swz;
  const char* aHalf0 = sA + wm * 16384;
  const char* bHalf0 = sB + (wn >> 1) * 16384;

  f32x4 acc[8][4] = {};
  const int nt = K >> 6;

  auto stageA = [&](int buf, int kt) {
#pragma unroll
    for (int i = 0; i < 4; ++i)
      gload_lds16(gA[i] + (size_t)kt * 64, (u16*)(sA + buf * 32768 + ldsOff[i]));
  };
  auto stageB = [&](int buf, int kt) {
#pragma unroll
    for (int i = 0; i < 4; ++i)
      gload_lds16(gB[i] + (size_t)kt * 64, (u16*)(sB + buf * 32768 + ldsOff[i]));
  };

  // prologue: tile 0 resident
  stageA(0, 0); stageB(0, 0);
  asm volatile("s_waitcnt vmcnt(0)" ::: "memory");
  __builtin_amdgcn_s_barrier();

  auto tile = [&](int kt, int buf) {
    bf16x8 af[4][2], bfr[2][2];
#pragma unroll
    for (int ph = 0; ph < 4; ++ph) {
      const int mh = ph >> 1;
      const int nh = (ph & 1) ^ mh;          // (0,0)(0,1)(1,1)(1,0)
      if (ph == 0 || ph == 2) {              // 8 A-frag ds_read_b128
#pragma unroll
        for (int mi = 0; mi < 4; ++mi)
#pragma unroll
          for (int ks = 0; ks < 2; ++ks)
            af[mi][ks] = *(const bf16x8*)(aHalf0 + buf * 32768 + aLaneOff +
                                          (mh * 64 + mi * 16) * 128 + ks * 64);
      }
      if (ph != 2) {                         // 4 B-frag ds_read_b128
#pragma unroll
        for (int ni = 0; ni < 2; ++ni)
#pragma unroll
          for (int ks = 0; ks < 2; ++ks)
            bfr[ni][ks] = *(const bf16x8*)(bHalf0 + buf * 32768 + bLaneOff +
                                           (nh * 2 + ni) * 2048 + ks * 64);
      }
      if (ph == 0 && kt + 1 < nt) stageA(buf ^ 1, kt + 1);
      if (ph == 1 && kt + 1 < nt) stageB(buf ^ 1, kt + 1);
      __builtin_amdgcn_s_barrier();
      __builtin_amdgcn_s_setprio(1);
#pragma unroll
      for (int mi = 0; mi < 4; ++mi)
#pragma unroll
        for (int ni = 0; ni < 2; ++ni)
#pragma unroll
          for (int ks = 0; ks < 2; ++ks)
            acc[mh * 4 + mi][nh * 2 + ni] = __builtin_amdgcn_mfma_f32_16x16x32_bf16(
                af[mi][ks], bfr[ni][ks], acc[mh * 4 + mi][nh * 2 + ni], 0, 0, 0);
      __builtin_amdgcn_s_setprio(0);
      __builtin_amdgcn_s_barrier();
    }
    asm volatile("s_waitcnt vmcnt(0)" ::: "memory");  // next tile resident
    __builtin_amdgcn_s_barrier();
  };

#pragma unroll 1
  for (int kt = 0; kt < nt; kt += 2) {
    tile(kt, 0);
    tile(kt + 1, 1);
  }

  // epilogue: C/D frag (16x16x32): col=lane&15, row=kg*4+j
  const int row0 = rowBase + wm * 128 + (kg << 2);
  const int col0 = colBase + wn * 64 + fr;
#pragma unroll
  for (int mi = 0; mi < 8; ++mi)
#pragma unroll
    for (int ni = 0; ni < 4; ++ni) {
      const int col = col0 + ni * 16;
      const int row = row0 + mi * 16;
      if (EPI == 0) {
        float* O = (float*)Obase;
        const float bv = bias[col];
#pragma unroll
        for (int j = 0; j < 4; ++j)
          O[(size_t)(row + j) * ldOut + col] = acc[mi][ni][j] + bv;
      } else if (EPI == 1) {
        u16* O = (u16*)Obase + (size_t)e * oStride;
#pragma unroll
        for (int j = 0; j < 4; ++j) {
          float v = acc[mi][ni][j];
          v = 0.5f * v * (1.0f + erff(v * 0.70710678118654752f));
          O[(size_t)(row + j) * ldOut + col] = f2bf(v);
        }
      } else {
        float* O = (float*)Obase + (size_t)e * oStride;
#pragma unroll
        for (int j = 0; j < 4; ++j)
          O[(size_t)(row + j) * ldOut + col] = acc[mi][ni][j];
      }
    }
}

// transpose+convert: in f32 [z][R][C] -> out bf16 [z][C][R]
__global__ void k_transcvt(const float* __restrict__ in, u16* __restrict__ out,
                           int R, int C) {
  const size_t bo = (size_t)blockIdx.z * R * C;
  in += bo; out += bo;
  __shared__ u16 tile[32][33];
  const int tx = threadIdx.x, ty = threadIdx.y;
  const int r0 = blockIdx.y << 5, c0 = blockIdx.x << 5;
#pragma unroll
  for (int j = 0; j < 4; ++j) {
    const int r = r0 + ty + j * 8;
    tile[ty + j * 8][tx] = f2bf(in[(size_t)r * C + c0 + tx]);
  }
  __syncthreads();
#pragma unroll
  for (int j = 0; j < 4; ++j) {
    const int c = c0 + ty + j * 8;
    out[(size_t)c * R + r0 + tx] = tile[tx][ty + j * 8];
  }
}

// embedding gather
__global__ void k_gather(const int* __restrict__ x, const float* __restrict__ emb,
                         float* __restrict__ h) {
  const int n = blockIdx.x, t = threadIdx.x;
  const int id = x[n];
  ((float4*)(h + (size_t)n * DM))[t] = ((const float4*)(emb + (size_t)id * DM))[t];
}

// fused LayerNorm (f32) -> xn bf16, + gating logits + softmax -> rw
__global__ void k_lngate(const float* __restrict__ h, const float* __restrict__ g,
                         const float* __restrict__ b, const float* __restrict__ gw,
                         const float* __restrict__ gb, u16* __restrict__ xnb,
                         float* __restrict__ rw) {
  const int n = blockIdx.x, t = threadIdx.x;
  const int wave = t >> 6, lane = t & 63;
  const float4 v = ((const float4*)(h + (size_t)n * DM))[t];
  float s = v.x + v.y + v.z + v.w;
  float q = v.x * v.x + v.y * v.y + v.z * v.z + v.w * v.w;
#pragma unroll
  for (int o = 32; o; o >>= 1) { s += __shfl_down(s, o, 64); q += __shfl_down(q, o, 64); }
  __shared__ float red[8];
  if (lane == 0) { red[wave] = s; red[wave + 4] = q; }
  __syncthreads();
  s = red[0] + red[1] + red[2] + red[3];
  q = red[4] + red[5] + red[6] + red[7];
  const float mu = s * (1.0f / DM);
  const float var = q * (1.0f / DM) - mu * mu;
  const float rs = rsqrtf(var + 1e-5f);
  const float4 gg = ((const float4*)g)[t];
  const float4 bb = ((const float4*)b)[t];
  float xv[4];
  xv[0] = (v.x - mu) * rs * gg.x + bb.x;
  xv[1] = (v.y - mu) * rs * gg.y + bb.y;
  xv[2] = (v.z - mu) * rs * gg.z + bb.z;
  xv[3] = (v.w - mu) * rs * gg.w + bb.w;
  ushort4 o4;
  o4.x = f2bf(xv[0]); o4.y = f2bf(xv[1]); o4.z = f2bf(xv[2]); o4.w = f2bf(xv[3]);
  ((ushort4*)(xnb + (size_t)n * DM))[t] = o4;
  float p[8];
#pragma unroll
  for (int e = 0; e < 8; ++e) p[e] = 0.0f;
  const float* gwp = gw + (size_t)t * 32;
#pragma unroll
  for (int j = 0; j < 4; ++j)
#pragma unroll
    for (int e = 0; e < 8; ++e) p[e] += xv[j] * gwp[j * 8 + e];
#pragma unroll
  for (int e = 0; e < 8; ++e)
#pragma unroll
    for (int o = 32; o; o >>= 1) p[e] += __shfl_down(p[e], o, 64);
  __shared__ float pr[4][8];
  if (lane == 0) {
#pragma unroll
    for (int e = 0; e < 8; ++e) pr[wave][e] = p[e];
  }
  __syncthreads();
  if (t == 0) {
    float lg[8], m = -1e30f;
#pragma unroll
    for (int e = 0; e < 8; ++e) {
      lg[e] = pr[0][e] + pr[1][e] + pr[2][e] + pr[3][e] + gb[e];
      m = fmaxf(m, lg[e]);
    }
    float ss = 0.0f;
#pragma unroll
    for (int e = 0; e < 8; ++e) { lg[e] = expf(lg[e] - m); ss += lg[e]; }
    const float inv = 1.0f / ss;
#pragma unroll
    for (int e = 0; e < 8; ++e) rw[(size_t)n * NE + e] = lg[e] * inv;
  }
}

// h += sum_e rw[n][e] * eo[n][e][:]; also emit h in bf16 for the head GEMM
__global__ void k_agg(float* __restrict__ h, u16* __restrict__ hbf,
                      const float* __restrict__ eo, const float* __restrict__ rw) {
  const int n = blockIdx.x, t = threadIdx.x;
  float w[8];
#pragma unroll
  for (int e = 0; e < 8; ++e) w[e] = rw[(size_t)n * NE + e];
  const float4* eo4 = (const float4*)(eo + (size_t)n * NE * DM);
  float4 a = ((float4*)(h + (size_t)n * DM))[t];
#pragma unroll
  for (int e = 0; e < 8; ++e) {
    const float4 x = eo4[e * (DM / 4) + t];
    a.x += w[e] * x.x; a.y += w[e] * x.y; a.z += w[e] * x.z; a.w += w[e] * x.w;
  }
  ((float4*)(h + (size_t)n * DM))[t] = a;
  ushort4 o4;
  o4.x = f2bf(a.x); o4.y = f2bf(a.y); o4.z = f2bf(a.z); o4.w = f2bf(a.w);
  ((ushort4*)(hbf + (size_t)n * DM))[t] = o4;
}

extern "C" void kernel_launch(void* const* d_in, const int* in_sizes, int n_in,
                              void* d_out, int out_size, void* d_ws, size_t ws_size,
                              hipStream_t stream) {
  const int*   x      = (const int*)d_in[0];
  const float* emb    = (const float*)d_in[1];
  const float* ln_g   = (const float*)d_in[2];
  const float* ln_b   = (const float*)d_in[3];
  const float* gate_w = (const float*)d_in[4];
  const float* gate_b = (const float*)d_in[5];
  const float* w1     = (const float*)d_in[6];
  const float* w2     = (const float*)d_in[7];
  const float* head_w = (const float*)d_in[8];
  const float* head_b = (const float*)d_in[9];

  float* logits  = (float*)d_out;
  float* experts = logits + (size_t)NTOK * NV;

  char* p = (char*)d_ws;
  auto carve = [&](size_t bytes) -> void* {
    void* r = (void*)p; p += (bytes + 255) & ~(size_t)255; return r;
  };
  float* h   = (float*)carve((size_t)NTOK * DM * 4);
  u16*   hbf = (u16*)  carve((size_t)NTOK * DM * 2);
  u16*   xnb = (u16*)  carve((size_t)NTOK * DM * 2);
  float* rw  = (float*)carve((size_t)NTOK * NE * 4);
  u16*   w1t = (u16*)  carve((size_t)NE * DM * DI * 2);
  u16*   w2t = (u16*)  carve((size_t)NE * DM * DI * 2);
  u16*   hwt = (u16*)  carve((size_t)NV * DM * 2);
  const size_t fixed = (size_t)(p - (char*)d_ws);
  const size_t eactOne = (size_t)NTOK * DI * 2;
  const bool batched = ws_size >= fixed + eactOne * NE;
  u16* eact = (u16*)carve(batched ? eactOne * NE : eactOne);

  // allow 128 KB dynamic LDS (idempotent; safe under graph capture)
  hipFuncSetAttribute((const void*)k_gemm256<0>,
                      hipFuncAttributeMaxDynamicSharedMemorySize, 131072);
  hipFuncSetAttribute((const void*)k_gemm256<1>,
                      hipFuncAttributeMaxDynamicSharedMemorySize, 131072);
  hipFuncSetAttribute((const void*)k_gemm256<2>,
                      hipFuncAttributeMaxDynamicSharedMemorySize, 131072);

  k_gather<<<dim3(NTOK), dim3(256), 0, stream>>>(x, emb, h);

  for (int l = 0; l < NL; ++l) {
    k_lngate<<<dim3(NTOK), dim3(256), 0, stream>>>(
        h, ln_g + (size_t)l * DM, ln_b + (size_t)l * DM,
        gate_w + (size_t)l * DM * NE, gate_b + (size_t)l * NE, xnb, rw);
    k_transcvt<<<dim3(DI / 32, DM / 32, NE), dim3(32, 8), 0, stream>>>(
        w1 + (size_t)l * NE * DM * DI, w1t, DM, DI);
    k_transcvt<<<dim3(DM / 32, DI / 32, NE), dim3(32, 8), 0, stream>>>(
        w2 + (size_t)l * NE * DM * DI, w2t, DI, DM);
    float* expertsL = experts + (size_t)l * NTOK * NE * DM;
    if (batched) {
      k_gemm256<1><<<dim3(NE * (DI / 256) * (NTOK / 256)), dim3(512), 131072, stream>>>(
          xnb, w1t, eact, nullptr, DM, NTOK / 256, DI / 256,
          (size_t)0, (size_t)DM * DI, (size_t)NTOK * DI, DI);
      k_gemm256<2><<<dim3(NE * (DM / 256) * (NTOK / 256)), dim3(512), 131072, stream>>>(
          eact, w2t, expertsL, nullptr, DI, NTOK / 256, DM / 256,
          (size_t)NTOK * DI, (size_t)DM * DI, (size_t)DM, NE * DM);
    } else {
      for (int e = 0; e < NE; ++e) {
        k_gemm256<1><<<dim3((DI / 256) * (NTOK / 256)), dim3(512), 131072, stream>>>(
            xnb, w1t + (size_t)e * DM * DI, eact, nullptr, DM, NTOK / 256, DI / 256,
            (size_t)0, (size_t)0, (size_t)0, DI);
        k_gemm256<2><<<dim3((DM / 256) * (NTOK / 256)), dim3(512), 131072, stream>>>(
            eact, w2t + (size_t)e * DM * DI, expertsL + (size_t)e * DM, nullptr,
            DI, NTOK / 256, DM / 256, (size_t)0, (size_t)0, (size_t)0, NE * DM);
      }
    }
    k_agg<<<dim3(NTOK), dim3(256), 0, stream>>>(h, hbf, expertsL, rw);
  }

  k_transcvt<<<dim3(NV / 32, DM / 32, 1), dim3(32, 8), 0, stream>>>(head_w, hwt, DM, NV);
  k_gemm256<0><<<dim3((NV / 256) * (NTOK / 256)), dim3(512), 131072, stream>>>(
      hbf, hwt, logits, head_b, DM, NTOK / 256, NV / 256,
      (size_t)0, (size_t)0, (size_t)0, NV);
}

// Round 3
// 2689.529 us; speedup vs baseline: 1.4640x; 1.0113x over previous
//
#include <hip/hip_runtime.h>
#include <hip/hip_bf16.h>
#include <stdint.h>

#define NTOK 8192   // B*T
#define DM   1024   // model dim
#define NE   8      // experts
#define DI   2048   // expert inner dim
#define NL   2      // layers
#define NV   32000  // vocab

typedef __attribute__((ext_vector_type(8))) __bf16 bf16x8;
typedef __attribute__((ext_vector_type(4))) float  f32x4;
typedef unsigned short u16;

__device__ __forceinline__ u16 f2bf(float f) {
  uint32_t u = __builtin_bit_cast(uint32_t, f);
  return (u16)((u + 0x7fffu + ((u >> 16) & 1u)) >> 16);  // RNE
}

__device__ __forceinline__ void gload_lds16(const u16* g, u16* l) {
  __builtin_amdgcn_global_load_lds(
      (const __attribute__((address_space(1))) void*)g,
      (__attribute__((address_space(3))) void*)l, 16, 0, 0);
}

// bijective chunked XCD swizzle (m204)
__device__ __forceinline__ int xcd_swz(int orig, int nwg) {
  const int x = orig & 7, i = orig >> 3;
  const int q = nwg >> 3, r = nwg & 7;
  return (x < r ? x * (q + 1) : r * (q + 1) + (x - r) * q) + i;
}

// ---------------------------------------------------------------------------
// 256x256 tile GEMM, 8 waves (2M x 4N). Pipeline granularity = K-half (32).
// LDS: A halves [4][256][32]bf16 (16 KB each), B same -> 128 KB total.
// Half-buffer for K-half g = g&3. While computing g, stage g+3:
//   steady-state entry wait = vmcnt(8) (2 groups x 4 loads in flight), never 0.
// [256][32] layout: row = 64 B -> wave frag ds_read_b128 covers 1024
// contiguous bytes = all 32 banks -> conflict-free, NO swizzle needed.
// Per K-half: 2 phases x {ds_read frags | stage | setprio(1) 16 MFMA setprio(0)}.
// EPI: 0 = +bias -> f32 (head), 1 = gelu -> bf16 (gemm1), 2 = f32 strided.
// ---------------------------------------------------------------------------
template <int EPI>
__global__ __launch_bounds__(512) void k_gemm256(
    const u16* __restrict__ Abase, const u16* __restrict__ Wbase,
    void* __restrict__ Obase, const float* __restrict__ bias,
    int K, int mBlks, int nBlks,
    size_t aStride, size_t wStride, size_t oStride, int ldOut) {
  extern __shared__ u16 lds[];
  const int logical = xcd_swz(blockIdx.x, gridDim.x);
  const int perE = mBlks * nBlks;
  const int e    = logical / perE;
  const int rem  = logical - e * perE;
  const int nb   = rem / mBlks;        // n-strip outer
  const int mb   = rem - nb * mBlks;   // m inner -> B-strip L2 reuse per XCD
  const int rowBase = mb << 8;
  const int colBase = nb << 8;
  const u16* A = Abase + (size_t)e * aStride;
  const u16* W = Wbase + (size_t)e * wStride;

  const int t = threadIdx.x;
  const int lane = t & 63, wave = t >> 6;
  const int wm = wave >> 2, wn = wave & 3;   // wave tile: rows wm*128, cols wn*64
  const int fr = lane & 15, kg = lane >> 4;

  char* sA = (char*)lds;           // 4 half-buffers x 16384 B
  char* sB = (char*)lds + 65536;

  // staging: thread t stages chunks c0=t, c1=t+512 of each 16 KB half
  // chunk c -> row c>>2, k-col (c&3)*8 elems; LDS dest linear c*16
  const int c0 = t, c1 = t + 512;
  const u16* gA0 = A + (size_t)(rowBase + (c0 >> 2)) * K + (c0 & 3) * 8;
  const u16* gA1 = A + (size_t)(rowBase + (c1 >> 2)) * K + (c1 & 3) * 8;
  const u16* gB0 = W + (size_t)(colBase + (c0 >> 2)) * K + (c0 & 3) * 8;
  const u16* gB1 = W + (size_t)(colBase + (c1 >> 2)) * K + (c1 & 3) * 8;
  const int lo0 = c0 * 16, lo1 = c1 * 16;

  auto stageA = [&](int g) {
    char* dst = sA + (g & 3) * 16384;
    gload_lds16(gA0 + (size_t)g * 32, (u16*)(dst + lo0));
    gload_lds16(gA1 + (size_t)g * 32, (u16*)(dst + lo1));
  };
  auto stageB = [&](int g) {
    char* dst = sB + (g & 3) * 16384;
    gload_lds16(gB0 + (size_t)g * 32, (u16*)(dst + lo0));
    gload_lds16(gB1 + (size_t)g * 32, (u16*)(dst + lo1));
  };

  f32x4 acc[8][4] = {};
  const int NG = K >> 5;   // number of K-halves (>= 4 for all our shapes)

  // fragment lane offsets within a half-buffer
  const int aOff = (wm * 128 + fr) * 64 + kg * 16;
  const int bOff = (wn * 64 + fr) * 64 + kg * 16;

  auto khalf = [&](int g, bool doStage) {
    __builtin_amdgcn_s_barrier();
    asm volatile("" ::: "memory");   // no ds_read hoisted above the barrier
    const char* aB = sA + (g & 3) * 16384 + aOff;
    const char* bB = sB + (g & 3) * 16384 + bOff;
    bf16x8 af[4], bv[4];
#pragma unroll
    for (int i = 0; i < 4; ++i) af[i] = *(const bf16x8*)(aB + i * 1024);
#pragma unroll
    for (int i = 0; i < 4; ++i) bv[i] = *(const bf16x8*)(bB + i * 1024);
    if (doStage) stageA(g + 3);
    __builtin_amdgcn_s_setprio(1);
#pragma unroll
    for (int mi = 0; mi < 4; ++mi)
#pragma unroll
      for (int ni = 0; ni < 4; ++ni)
        acc[mi][ni] = __builtin_amdgcn_mfma_f32_16x16x32_bf16(
            af[mi], bv[ni], acc[mi][ni], 0, 0, 0);
    __builtin_amdgcn_s_setprio(0);
    __builtin_amdgcn_s_barrier();    // phase alignment (no data hazard)
#pragma unroll
    for (int i = 0; i < 4; ++i) af[i] = *(const bf16x8*)(aB + 4096 + i * 1024);
    if (doStage) stageB(g + 3);
    __builtin_amdgcn_s_setprio(1);
#pragma unroll
    for (int mi = 0; mi < 4; ++mi)
#pragma unroll
      for (int ni = 0; ni < 4; ++ni)
        acc[4 + mi][ni] = __builtin_amdgcn_mfma_f32_16x16x32_bf16(
            af[mi], bv[ni], acc[4 + mi][ni], 0, 0, 0);
    __builtin_amdgcn_s_setprio(0);
  };

  // prologue: 3 groups in flight
  stageA(0); stageB(0);
  stageA(1); stageB(1);
  stageA(2); stageB(2);

#pragma unroll 1
  for (int g = 0; g < NG - 3; ++g) {
    asm volatile("s_waitcnt vmcnt(8)" ::: "memory");
    khalf(g, true);
  }
  asm volatile("s_waitcnt vmcnt(8)" ::: "memory");
  khalf(NG - 3, false);
  asm volatile("s_waitcnt vmcnt(4)" ::: "memory");
  khalf(NG - 2, false);
  asm volatile("s_waitcnt vmcnt(0)" ::: "memory");
  khalf(NG - 1, false);

  // epilogue: C/D frag (16x16x32): col=lane&15, row=(lane>>4)*4+j
  const int row0 = rowBase + wm * 128 + (kg << 2);
  const int col0 = colBase + wn * 64 + fr;
#pragma unroll
  for (int mi = 0; mi < 8; ++mi)
#pragma unroll
    for (int ni = 0; ni < 4; ++ni) {
      const int col = col0 + ni * 16;
      const int row = row0 + mi * 16;
      if (EPI == 0) {
        float* O = (float*)Obase;
        const float bv2 = bias[col];
#pragma unroll
        for (int j = 0; j < 4; ++j)
          O[(size_t)(row + j) * ldOut + col] = acc[mi][ni][j] + bv2;
      } else if (EPI == 1) {
        u16* O = (u16*)Obase + (size_t)e * oStride;
#pragma unroll
        for (int j = 0; j < 4; ++j) {
          float v = acc[mi][ni][j];
          v = 0.5f * v * (1.0f + erff(v * 0.70710678118654752f));
          O[(size_t)(row + j) * ldOut + col] = f2bf(v);
        }
      } else {
        float* O = (float*)Obase + (size_t)e * oStride;
#pragma unroll
        for (int j = 0; j < 4; ++j)
          O[(size_t)(row + j) * ldOut + col] = acc[mi][ni][j];
      }
    }
}

// transpose+convert: in f32 [z][R][C] -> out bf16 [z][C][R]
__global__ void k_transcvt(const float* __restrict__ in, u16* __restrict__ out,
                           int R, int C) {
  const size_t bo = (size_t)blockIdx.z * R * C;
  in += bo; out += bo;
  __shared__ u16 tile[32][33];
  const int tx = threadIdx.x, ty = threadIdx.y;
  const int r0 = blockIdx.y << 5, c0 = blockIdx.x << 5;
#pragma unroll
  for (int j = 0; j < 4; ++j) {
    const int r = r0 + ty + j * 8;
    tile[ty + j * 8][tx] = f2bf(in[(size_t)r * C + c0 + tx]);
  }
  __syncthreads();
#pragma unroll
  for (int j = 0; j < 4; ++j) {
    const int c = c0 + ty + j * 8;
    out[(size_t)c * R + r0 + tx] = tile[tx][ty + j * 8];
  }
}

// embedding gather
__global__ void k_gather(const int* __restrict__ x, const float* __restrict__ emb,
                         float* __restrict__ h) {
  const int n = blockIdx.x, t = threadIdx.x;
  const int id = x[n];
  ((float4*)(h + (size_t)n * DM))[t] = ((const float4*)(emb + (size_t)id * DM))[t];
}

// fused LayerNorm (f32) -> xn bf16, + gating logits + softmax -> rw
__global__ void k_lngate(const float* __restrict__ h, const float* __restrict__ g,
                         const float* __restrict__ b, const float* __restrict__ gw,
                         const float* __restrict__ gb, u16* __restrict__ xnb,
                         float* __restrict__ rw) {
  const int n = blockIdx.x, t = threadIdx.x;
  const int wave = t >> 6, lane = t & 63;
  const float4 v = ((const float4*)(h + (size_t)n * DM))[t];
  float s = v.x + v.y + v.z + v.w;
  float q = v.x * v.x + v.y * v.y + v.z * v.z + v.w * v.w;
#pragma unroll
  for (int o = 32; o; o >>= 1) { s += __shfl_down(s, o, 64); q += __shfl_down(q, o, 64); }
  __shared__ float red[8];
  if (lane == 0) { red[wave] = s; red[wave + 4] = q; }
  __syncthreads();
  s = red[0] + red[1] + red[2] + red[3];
  q = red[4] + red[5] + red[6] + red[7];
  const float mu = s * (1.0f / DM);
  const float var = q * (1.0f / DM) - mu * mu;
  const float rs = rsqrtf(var + 1e-5f);
  const float4 gg = ((const float4*)g)[t];
  const float4 bb = ((const float4*)b)[t];
  float xv[4];
  xv[0] = (v.x - mu) * rs * gg.x + bb.x;
  xv[1] = (v.y - mu) * rs * gg.y + bb.y;
  xv[2] = (v.z - mu) * rs * gg.z + bb.z;
  xv[3] = (v.w - mu) * rs * gg.w + bb.w;
  ushort4 o4;
  o4.x = f2bf(xv[0]); o4.y = f2bf(xv[1]); o4.z = f2bf(xv[2]); o4.w = f2bf(xv[3]);
  ((ushort4*)(xnb + (size_t)n * DM))[t] = o4;
  float p[8];
#pragma unroll
  for (int e = 0; e < 8; ++e) p[e] = 0.0f;
  const float* gwp = gw + (size_t)t * 32;
#pragma unroll
  for (int j = 0; j < 4; ++j)
#pragma unroll
    for (int e = 0; e < 8; ++e) p[e] += xv[j] * gwp[j * 8 + e];
#pragma unroll
  for (int e = 0; e < 8; ++e)
#pragma unroll
    for (int o = 32; o; o >>= 1) p[e] += __shfl_down(p[e], o, 64);
  __shared__ float pr[4][8];
  if (lane == 0) {
#pragma unroll
    for (int e = 0; e < 8; ++e) pr[wave][e] = p[e];
  }
  __syncthreads();
  if (t == 0) {
    float lg[8], m = -1e30f;
#pragma unroll
    for (int e = 0; e < 8; ++e) {
      lg[e] = pr[0][e] + pr[1][e] + pr[2][e] + pr[3][e] + gb[e];
      m = fmaxf(m, lg[e]);
    }
    float ss = 0.0f;
#pragma unroll
    for (int e = 0; e < 8; ++e) { lg[e] = expf(lg[e] - m); ss += lg[e]; }
    const float inv = 1.0f / ss;
#pragma unroll
    for (int e = 0; e < 8; ++e) rw[(size_t)n * NE + e] = lg[e] * inv;
  }
}

// h += sum_e rw[n][e] * eo[n][e][:]; also emit h in bf16 for the head GEMM
__global__ void k_agg(float* __restrict__ h, u16* __restrict__ hbf,
                      const float* __restrict__ eo, const float* __restrict__ rw) {
  const int n = blockIdx.x, t = threadIdx.x;
  float w[8];
#pragma unroll
  for (int e = 0; e < 8; ++e) w[e] = rw[(size_t)n * NE + e];
  const float4* eo4 = (const float4*)(eo + (size_t)n * NE * DM);
  float4 a = ((float4*)(h + (size_t)n * DM))[t];
#pragma unroll
  for (int e = 0; e < 8; ++e) {
    const float4 x = eo4[e * (DM / 4) + t];
    a.x += w[e] * x.x; a.y += w[e] * x.y; a.z += w[e] * x.z; a.w += w[e] * x.w;
  }
  ((float4*)(h + (size_t)n * DM))[t] = a;
  ushort4 o4;
  o4.x = f2bf(a.x); o4.y = f2bf(a.y); o4.z = f2bf(a.z); o4.w = f2bf(a.w);
  ((ushort4*)(hbf + (size_t)n * DM))[t] = o4;
}

extern "C" void kernel_launch(void* const* d_in, const int* in_sizes, int n_in,
                              void* d_out, int out_size, void* d_ws, size_t ws_size,
                              hipStream_t stream) {
  const int*   x      = (const int*)d_in[0];
  const float* emb    = (const float*)d_in[1];
  const float* ln_g   = (const float*)d_in[2];
  const float* ln_b   = (const float*)d_in[3];
  const float* gate_w = (const float*)d_in[4];
  const float* gate_b = (const float*)d_in[5];
  const float* w1     = (const float*)d_in[6];
  const float* w2     = (const float*)d_in[7];
  const float* head_w = (const float*)d_in[8];
  const float* head_b = (const float*)d_in[9];

  float* logits  = (float*)d_out;
  float* experts = logits + (size_t)NTOK * NV;

  char* p = (char*)d_ws;
  auto carve = [&](size_t bytes) -> void* {
    void* r = (void*)p; p += (bytes + 255) & ~(size_t)255; return r;
  };
  float* h   = (float*)carve((size_t)NTOK * DM * 4);
  u16*   hbf = (u16*)  carve((size_t)NTOK * DM * 2);
  u16*   xnb = (u16*)  carve((size_t)NTOK * DM * 2);
  float* rw  = (float*)carve((size_t)NTOK * NE * 4);
  u16*   w1t = (u16*)  carve((size_t)NE * DM * DI * 2);
  u16*   w2t = (u16*)  carve((size_t)NE * DM * DI * 2);
  u16*   hwt = (u16*)  carve((size_t)NV * DM * 2);
  const size_t fixed = (size_t)(p - (char*)d_ws);
  const size_t eactOne = (size_t)NTOK * DI * 2;
  const bool batched = ws_size >= fixed + eactOne * NE;
  u16* eact = (u16*)carve(batched ? eactOne * NE : eactOne);

  hipFuncSetAttribute((const void*)k_gemm256<0>,
                      hipFuncAttributeMaxDynamicSharedMemorySize, 131072);
  hipFuncSetAttribute((const void*)k_gemm256<1>,
                      hipFuncAttributeMaxDynamicSharedMemorySize, 131072);
  hipFuncSetAttribute((const void*)k_gemm256<2>,
                      hipFuncAttributeMaxDynamicSharedMemorySize, 131072);

  k_gather<<<dim3(NTOK), dim3(256), 0, stream>>>(x, emb, h);

  for (int l = 0; l < NL; ++l) {
    k_lngate<<<dim3(NTOK), dim3(256), 0, stream>>>(
        h, ln_g + (size_t)l * DM, ln_b + (size_t)l * DM,
        gate_w + (size_t)l * DM * NE, gate_b + (size_t)l * NE, xnb, rw);
    k_transcvt<<<dim3(DI / 32, DM / 32, NE), dim3(32, 8), 0, stream>>>(
        w1 + (size_t)l * NE * DM * DI, w1t, DM, DI);
    k_transcvt<<<dim3(DM / 32, DI / 32, NE), dim3(32, 8), 0, stream>>>(
        w2 + (size_t)l * NE * DM * DI, w2t, DI, DM);
    float* expertsL = experts + (size_t)l * NTOK * NE * DM;
    if (batched) {
      k_gemm256<1><<<dim3(NE * (DI / 256) * (NTOK / 256)), dim3(512), 131072, stream>>>(
          xnb, w1t, eact, nullptr, DM, NTOK / 256, DI / 256,
          (size_t)0, (size_t)DM * DI, (size_t)NTOK * DI, DI);
      k_gemm256<2><<<dim3(NE * (DM / 256) * (NTOK / 256)), dim3(512), 131072, stream>>>(
          eact, w2t, expertsL, nullptr, DI, NTOK / 256, DM / 256,
          (size_t)NTOK * DI, (size_t)DM * DI, (size_t)DM, NE * DM);
    } else {
      for (int e = 0; e < NE; ++e) {
        k_gemm256<1><<<dim3((DI / 256) * (NTOK / 256)), dim3(512), 131072, stream>>>(
            xnb, w1t + (size_t)e * DM * DI, eact, nullptr, DM, NTOK / 256, DI / 256,
            (size_t)0, (size_t)0, (size_t)0, DI);
        k_gemm256<2><<<dim3((DM / 256) * (NTOK / 256)), dim3(512), 131072, stream>>>(
            eact, w2t + (size_t)e * DM * DI, expertsL + (size_t)e * DM, nullptr,
            DI, NTOK / 256, DM / 256, (size_t)0, (size_t)0, (size_t)0, NE * DM);
      }
    }
    k_agg<<<dim3(NTOK), dim3(256), 0, stream>>>(h, hbf, expertsL, rw);
  }

  k_transcvt<<<dim3(NV / 32, DM / 32, 1), dim3(32, 8), 0, stream>>>(head_w, hwt, DM, NV);
  k_gemm256<0><<<dim3((NV / 256) * (NTOK / 256)), dim3(512), 131072, stream>>>(
      hbf, hwt, logits, head_b, DM, NTOK / 256, NV / 256,
      (size_t)0, (size_t)0, (size_t)0, NV);
}